// Round 2
// baseline (572.356 us; speedup 1.0000x reference)
//
#include <hip/hip_runtime.h>
#include <hip/hip_bf16.h>
#include <stdint.h>

typedef __bf16 bf16;
typedef __bf16 bf16x8 __attribute__((ext_vector_type(8)));
typedef __bf16 bf16x4 __attribute__((ext_vector_type(4)));
typedef float f32x4 __attribute__((ext_vector_type(4)));

#define E_DIM 2048
#define HEADS 16
#define HD 128
#define SEQ 2048
#define BATCH 2
#define NTOK 4096
#define NSLOT 8

__device__ __forceinline__ void gload_lds16(const void* g, void* lds) {
  __builtin_amdgcn_global_load_lds(
      (const __attribute__((address_space(1))) uint32_t*)g,
      (__attribute__((address_space(3))) uint32_t*)lds, 16, 0, 0);
}

// ---------------- f32 -> bf16 convert, 8 elems/thread, grid-stride ----------------
__global__ __launch_bounds__(256) void cvt_f32_bf16_kernel(
    const float* __restrict__ src, bf16* __restrict__ dst, int n8)
{
  for (int i = blockIdx.x * 256 + threadIdx.x; i < n8; i += gridDim.x * 256) {
    const f32x4 a = *(const f32x4*)(src + i * 8);
    const f32x4 b = *(const f32x4*)(src + i * 8 + 4);
    bf16x8 o;
#pragma unroll
    for (int j = 0; j < 4; j++) { o[j] = (bf16)a[j]; o[4 + j] = (bf16)b[j]; }
    *(bf16x8*)(dst + i * 8) = o;
  }
}

struct ProjArgs {
  const bf16* W[4];
  const float* bias[4];
  void* out[4];
  int mode[4];   // 0: f32 row-major [M][N]; 1: bf16 [B,H,S,D]; 2: bf16 [B,H,D,S]
};

// ---------------- NT GEMM: C = A @ W^T + bias, bf16 in, fp32 acc ----------------
// A [M][K] row-major bf16, W [N][K] row-major bf16. 128x128 tile, BK=32, 4 waves.
__global__ __launch_bounds__(256) void gemm_nt_kernel(
    const bf16* __restrict__ A, ProjArgs pa, int M, int N, int K)
{
  __shared__ bf16 As[128 * 32];
  __shared__ bf16 Bs[128 * 32];

  const int z = blockIdx.z;
  const bf16* __restrict__ W = pa.W[z];
  const float* __restrict__ bias = pa.bias[z];
  void* __restrict__ out = pa.out[z];
  const int mode = pa.mode[z];

  const int tid = threadIdx.x;
  const int lane = tid & 63;
  const int w = tid >> 6;
  const int wr = w >> 1, wc = w & 1;
  const int g = lane >> 4, c = lane & 15;
  const int bm = blockIdx.x, bn = blockIdx.y;

  f32x4 acc[4][4] = {};

  const int srow = lane >> 2;          // 0..15
  const int scol = (lane & 3) * 8;     // 0,8,16,24
  const bf16* Ab = A + (size_t)(bm * 128 + srow) * K + scol;
  const bf16* Wb = W + (size_t)(bn * 128 + srow) * K + scol;

  for (int k0 = 0; k0 < K; k0 += 32) {
    __syncthreads();
#pragma unroll
    for (int i = 0; i < 2; ++i) {
      const int chunk = w * 2 + i;     // 0..7, each 1024B = 16 rows x 32 cols
      gload_lds16(Ab + (size_t)(chunk * 16) * K + k0, (char*)As + chunk * 1024);
      gload_lds16(Wb + (size_t)(chunk * 16) * K + k0, (char*)Bs + chunk * 1024);
    }
    __syncthreads();
    bf16x8 af[4], bfr[4];
#pragma unroll
    for (int m = 0; m < 4; m++)
      af[m] = *(const bf16x8*)(As + (wr * 64 + m * 16 + c) * 32 + g * 8);
#pragma unroll
    for (int n = 0; n < 4; n++)
      bfr[n] = *(const bf16x8*)(Bs + (wc * 64 + n * 16 + c) * 32 + g * 8);
#pragma unroll
    for (int m = 0; m < 4; m++)
#pragma unroll
      for (int n = 0; n < 4; n++)
        acc[m][n] = __builtin_amdgcn_mfma_f32_16x16x32_bf16(af[m], bfr[n], acc[m][n], 0, 0, 0);
  }

  // epilogue: D[r][c]: col = lane&15, row = (lane>>4)*4 + j
#pragma unroll
  for (int m = 0; m < 4; m++) {
#pragma unroll
    for (int n = 0; n < 4; n++) {
      const int col = bn * 128 + wc * 64 + n * 16 + c;
      const float bv = bias[col];
#pragma unroll
      for (int j = 0; j < 4; j++) {
        const int row = bm * 128 + wr * 64 + m * 16 + g * 4 + j;
        const float v = acc[m][n][j] + bv;
        if (mode == 0) {
          ((float*)out)[(size_t)row * N + col] = v;
        } else {
          const int b = row >> 11, s = row & 2047;
          const int h = col >> 7, d = col & 127;
          size_t idx;
          if (mode == 1) idx = (((size_t)(b * HEADS + h)) * SEQ + s) * HD + d;
          else           idx = (((size_t)(b * HEADS + h)) * HD + d) * SEQ + s;
          ((bf16*)out)[idx] = (bf16)v;
        }
      }
    }
  }
}

// ---------------- slots projections: tk/tv = slots @ W^T + b, f32 [8][2048] ----------------
__global__ __launch_bounds__(256) void slots_proj_kernel(
    const float* __restrict__ slots,
    const float* __restrict__ Wk, const float* __restrict__ bk,
    const float* __restrict__ Wv, const float* __restrict__ bv,
    float* __restrict__ tk, float* __restrict__ tv)
{
  const int col = blockIdx.x * 256 + threadIdx.x;
  const int slot = blockIdx.y;
  const int mat = blockIdx.z;
  const float* W = mat ? Wv : Wk;
  const float* bias = mat ? bv : bk;
  float* out = mat ? tv : tk;
  const float* xr = slots + (size_t)slot * E_DIM;
  const float* wr = W + (size_t)col * E_DIM;
  float acc = 0.f;
  for (int k = 0; k < E_DIM; k += 4) {
    const f32x4 a = *(const f32x4*)(xr + k);
    const f32x4 b4 = *(const f32x4*)(wr + k);
#pragma unroll
    for (int i = 0; i < 4; i++) acc += a[i] * b4[i];
  }
  out[(size_t)slot * E_DIM + col] = acc + bias[col];
}

// ---------------- flash attention (full, no mask) ----------------
// Q,K: bf16 [B,H,S,D]; Vt: bf16 [B,H,D,S]; out: bf16 [B,S,E] (heads merged).
// Block: 4 waves, 128 q rows (32/wave). KV tile = 64. Swapped QK^T: S^T = mfma(K, Q).
__global__ __launch_bounds__(256) void flash_attn_kernel(
    const bf16* __restrict__ Qg, const bf16* __restrict__ Kg,
    const bf16* __restrict__ Vtg, bf16* __restrict__ Og)
{
  __shared__ char Ks[64 * 256];    // [kv][d] bf16, 256B rows, XOR-swizzled
  __shared__ char Vs[128 * 128];   // [d][kv] bf16, 128B rows, XOR-swizzled
  __shared__ char Ps[4 * 32 * 128];// per-wave [q32][kv64] bf16, swizzled

  const int tid = threadIdx.x;
  const int lane = tid & 63;
  const int w = tid >> 6;
  const int g = lane >> 4, c = lane & 15;
  const int bh = blockIdx.y;
  const int b = bh >> 4, h = bh & 15;
  const int q0 = blockIdx.x * 128 + w * 32;

  const bf16* Qb = Qg + ((size_t)bh * SEQ + q0) * HD;
  const bf16* Kb = Kg + (size_t)bh * SEQ * HD;
  const bf16* Vb = Vtg + (size_t)bh * HD * SEQ;
  char* Pw = Ps + w * 4096;

  // Q fragments (B operand): qf[kk][n][j] = Q[n*16+c][kk*32+g*8+j]
  bf16x8 qf[4][2];
#pragma unroll
  for (int kk = 0; kk < 4; kk++)
#pragma unroll
    for (int n = 0; n < 2; n++)
      qf[kk][n] = *(const bf16x8*)(Qb + (size_t)(n * 16 + c) * HD + kk * 32 + g * 8);

  f32x4 acc[2][8] = {};
  float mrun[2] = {-1e30f, -1e30f};
  float lrun[2] = {0.f, 0.f};
  const float sc2 = 0.08838834764831845f * 1.4426950408889634f; // 1/sqrt(D) * log2(e)

  for (int kv0 = 0; kv0 < SEQ; kv0 += 64) {
    __syncthreads();
    // stage K tile (16KB) + Vt tile (16KB); linear LDS dest, inverse-swizzled source
#pragma unroll
    for (int i = 0; i < 4; i++) {
      const int chunk = w * 4 + i;
      const int p = chunk * 1024 + lane * 16;
      {
        const int r = p >> 8;                       // kv row
        const int sl = ((p >> 4) & 15) ^ (r & 7);   // 16B slot within row
        gload_lds16(Kb + (size_t)(kv0 + r) * HD + sl * 8, Ks + chunk * 1024);
      }
      {
        const int r = p >> 7;                       // d row
        const int sl = ((p >> 4) & 7) ^ (r & 7);
        gload_lds16(Vb + (size_t)r * SEQ + kv0 + sl * 8, Vs + chunk * 1024);
      }
    }
    __syncthreads();

    // S^T[kv][q] = K · Q^T
    f32x4 st[4][2] = {};
#pragma unroll
    for (int kk = 0; kk < 4; kk++) {
      bf16x8 kf[4];
#pragma unroll
      for (int kfr = 0; kfr < 4; kfr++) {
        const int r = kfr * 16 + c;
        const int sl = (kk * 4 + g) ^ (r & 7);
        kf[kfr] = *(const bf16x8*)(Ks + r * 256 + sl * 16);
      }
#pragma unroll
      for (int kfr = 0; kfr < 4; kfr++)
#pragma unroll
        for (int n = 0; n < 2; n++)
          st[kfr][n] = __builtin_amdgcn_mfma_f32_16x16x32_bf16(kf[kfr], qf[kk][n], st[kfr][n], 0, 0, 0);
    }

    // online softmax; lane holds kv = kfr*16 + g*4 + j for q = n*16 + c
    float fsc[2];
#pragma unroll
    for (int n = 0; n < 2; n++) {
      float lm = -1e30f;
#pragma unroll
      for (int kfr = 0; kfr < 4; kfr++)
#pragma unroll
        for (int j = 0; j < 4; j++) {
          const float sv = st[kfr][n][j] * sc2;
          st[kfr][n][j] = sv;
          lm = fmaxf(lm, sv);
        }
      lm = fmaxf(lm, __shfl_xor(lm, 16));
      lm = fmaxf(lm, __shfl_xor(lm, 32));
      const float mn = fmaxf(mrun[n], lm);
      fsc[n] = exp2f(mrun[n] - mn);
      mrun[n] = mn;
      float ps = 0.f;
#pragma unroll
      for (int kfr = 0; kfr < 4; kfr++)
#pragma unroll
        for (int j = 0; j < 4; j++) {
          const float pp = exp2f(st[kfr][n][j] - mn);
          st[kfr][n][j] = pp;
          ps += pp;
        }
      ps += __shfl_xor(ps, 16);
      ps += __shfl_xor(ps, 32);
      lrun[n] = lrun[n] * fsc[n] + ps;
    }

    // rescale O accumulator: acc[m][*] row q = m*16 + g*4 + j
#pragma unroll
    for (int m = 0; m < 2; m++)
#pragma unroll
      for (int j = 0; j < 4; j++) {
        const float fj = __shfl(fsc[m], (lane & 48) | (g * 4 + j));
#pragma unroll
        for (int n = 0; n < 8; n++) acc[m][n][j] *= fj;
      }

    // write P (bf16) to per-wave LDS [q][kv], swizzled
#pragma unroll
    for (int n = 0; n < 2; n++)
#pragma unroll
      for (int kfr = 0; kfr < 4; kfr++) {
        bf16x4 pk;
#pragma unroll
        for (int j = 0; j < 4; j++) pk[j] = (bf16)st[kfr][n][j];
        const int q = n * 16 + c;
        const int L = q * 128 + kfr * 32 + g * 8;
        *(bf16x4*)(Pw + (L ^ ((q & 7) << 4))) = pk;
      }

    // O += P · V : A = P[q][kv], B = Vt[d][kv] (as B[k][n] with k=kv, n=d)
#pragma unroll
    for (int kk = 0; kk < 2; kk++) {
      bf16x8 pf[2];
#pragma unroll
      for (int m = 0; m < 2; m++) {
        const int q = m * 16 + c;
        const int L = q * 128 + kk * 64 + g * 16;
        pf[m] = *(const bf16x8*)(Pw + (L ^ ((q & 7) << 4)));
      }
#pragma unroll
      for (int n = 0; n < 8; n++) {
        const int d = n * 16 + c;
        const int Lv = d * 128 + kk * 64 + g * 16;
        const bf16x8 vf = *(const bf16x8*)(Vs + (Lv ^ ((d & 7) << 4)));
#pragma unroll
        for (int m = 0; m < 2; m++)
          acc[m][n] = __builtin_amdgcn_mfma_f32_16x16x32_bf16(pf[m], vf, acc[m][n], 0, 0, 0);
      }
    }
  }

  // epilogue: normalize and write [B,S,E]
#pragma unroll
  for (int m = 0; m < 2; m++) {
#pragma unroll
    for (int j = 0; j < 4; j++) {
      const float lb = __shfl(lrun[m], (lane & 48) | (g * 4 + j));
      const float linv = 1.0f / lb;
      const int s = q0 + m * 16 + g * 4 + j;
#pragma unroll
      for (int n = 0; n < 8; n++) {
        const int e = h * HD + n * 16 + c;
        Og[((size_t)b * SEQ + s) * E_DIM + e] = (bf16)(acc[m][n][j] * linv);
      }
    }
  }
}

// ---------------- thought attention: add per-row cross-attn over 8 slots ----------------
// TQ bf16 [B,H,S,D]; TK,TV f32 [8][E]; O bf16 [B,S,E] (read-modify-write add)
__global__ __launch_bounds__(256) void thought_attn_kernel(
    const bf16* __restrict__ TQ, const float* __restrict__ TK,
    const float* __restrict__ TV, bf16* __restrict__ O)
{
  const int tid = threadIdx.x;
  const int lane = tid & 63;
  const int w = tid >> 6;
  const size_t row = (size_t)blockIdx.x * 4 + w;   // bh*SEQ + s
  const int bh = (int)(row >> 11);
  const int s = (int)(row & 2047);
  const int b = bh >> 4, h = bh & 15;
  const int slot = lane >> 3;
  const int dp = (lane & 7) * 16;

  const bf16* qrow = TQ + row * HD + dp;
  const float* krow = TK + (size_t)slot * E_DIM + h * HD + dp;
  const float* vrow = TV + (size_t)slot * E_DIM + h * HD + dp;

  const bf16x8 q0v = *(const bf16x8*)(qrow);
  const bf16x8 q1v = *(const bf16x8*)(qrow + 8);
  float qv[16];
#pragma unroll
  for (int i = 0; i < 8; i++) { qv[i] = (float)q0v[i]; qv[8 + i] = (float)q1v[i]; }

  float kv[16], vv[16];
#pragma unroll
  for (int t = 0; t < 4; t++) {
    const f32x4 kq = *(const f32x4*)(krow + t * 4);
    const f32x4 vq = *(const f32x4*)(vrow + t * 4);
#pragma unroll
    for (int i = 0; i < 4; i++) { kv[t * 4 + i] = kq[i]; vv[t * 4 + i] = vq[i]; }
  }

  float dot = 0.f;
#pragma unroll
  for (int i = 0; i < 16; i++) dot += qv[i] * kv[i];
  dot += __shfl_xor(dot, 1);
  dot += __shfl_xor(dot, 2);
  dot += __shfl_xor(dot, 4);
  dot *= 0.08838834764831845f;

  float mx = dot;
  mx = fmaxf(mx, __shfl_xor(mx, 8));
  mx = fmaxf(mx, __shfl_xor(mx, 16));
  mx = fmaxf(mx, __shfl_xor(mx, 32));
  const float p = __expf(dot - mx);
  float den = p;
  den += __shfl_xor(den, 8);
  den += __shfl_xor(den, 16);
  den += __shfl_xor(den, 32);
  const float pn = p / den;

  float ov[16];
#pragma unroll
  for (int i = 0; i < 16; i++) ov[i] = pn * vv[i];
#pragma unroll
  for (int i = 0; i < 16; i++) {
    ov[i] += __shfl_xor(ov[i], 8);
    ov[i] += __shfl_xor(ov[i], 16);
    ov[i] += __shfl_xor(ov[i], 32);
  }
  if (slot == 0) {
    bf16* orow = O + ((size_t)b * SEQ + s) * E_DIM + h * HD + dp;
    const bf16x8 o0 = *(const bf16x8*)(orow);
    const bf16x8 o1 = *(const bf16x8*)(orow + 8);
    bf16x8 r0, r1;
#pragma unroll
    for (int i = 0; i < 8; i++) {
      r0[i] = (bf16)((float)o0[i] + ov[i]);
      r1[i] = (bf16)((float)o1[i] + ov[8 + i]);
    }
    *(bf16x8*)(orow) = r0;
    *(bf16x8*)(orow + 8) = r1;
  }
}

// ---------------- layernorm over E, one row per block ----------------
__global__ __launch_bounds__(256) void layernorm_kernel(
    const bf16* __restrict__ X, const float* __restrict__ gamma,
    const float* __restrict__ beta, bf16* __restrict__ Y)
{
  __shared__ float wsum[4], wsq[4];
  const int tid = threadIdx.x;
  const int lane = tid & 63;
  const int w = tid >> 6;
  const size_t base = (size_t)blockIdx.x * E_DIM + tid * 8;
  const bf16x8 xv = *(const bf16x8*)(X + base);
  float v[8];
  float s = 0.f, sq = 0.f;
#pragma unroll
  for (int i = 0; i < 8; i++) { v[i] = (float)xv[i]; s += v[i]; sq += v[i] * v[i]; }
#pragma unroll
  for (int d = 1; d < 64; d <<= 1) { s += __shfl_xor(s, d); sq += __shfl_xor(sq, d); }
  if (lane == 0) { wsum[w] = s; wsq[w] = sq; }
  __syncthreads();
  const float ts = wsum[0] + wsum[1] + wsum[2] + wsum[3];
  const float tq2 = wsq[0] + wsq[1] + wsq[2] + wsq[3];
  const float mean = ts * (1.f / E_DIM);
  const float var = tq2 * (1.f / E_DIM) - mean * mean;
  const float rstd = rsqrtf(var + 1e-5f);
  const f32x4 g0 = *(const f32x4*)(gamma + tid * 8);
  const f32x4 g1 = *(const f32x4*)(gamma + tid * 8 + 4);
  const f32x4 b0 = *(const f32x4*)(beta + tid * 8);
  const f32x4 b1 = *(const f32x4*)(beta + tid * 8 + 4);
  bf16x8 outv;
#pragma unroll
  for (int i = 0; i < 4; i++) {
    outv[i]     = (bf16)((v[i]     - mean) * rstd * g0[i] + b0[i]);
    outv[4 + i] = (bf16)((v[4 + i] - mean) * rstd * g1[i] + b1[i]);
  }
  *(bf16x8*)(Y + base) = outv;
}

extern "C" void kernel_launch(void* const* d_in, const int* in_sizes, int n_in,
                              void* d_out, int out_size, void* d_ws, size_t ws_size,
                              hipStream_t stream) {
  (void)in_sizes; (void)n_in; (void)out_size; (void)ws_size;
  const float* x     = (const float*)d_in[0];
  const float* slots = (const float*)d_in[1];
  const float* Wq  = (const float*)d_in[2];   const float* bq  = (const float*)d_in[3];
  const float* Wk  = (const float*)d_in[4];   const float* bk  = (const float*)d_in[5];
  const float* Wv  = (const float*)d_in[6];   const float* bv  = (const float*)d_in[7];
  const float* Wtq = (const float*)d_in[8];   const float* btq = (const float*)d_in[9];
  const float* Wtk = (const float*)d_in[10];  const float* btk = (const float*)d_in[11];
  const float* Wtv = (const float*)d_in[12];  const float* btv = (const float*)d_in[13];
  const float* Wo  = (const float*)d_in[14];  const float* bo  = (const float*)d_in[15];
  const float* gamma = (const float*)d_in[16];
  const float* beta  = (const float*)d_in[17];

  uint8_t* ws = (uint8_t*)d_ws;
  const size_t BUF  = (size_t)NTOK * E_DIM * sizeof(bf16);    // 16 MiB (activations)
  const size_t WBUF = (size_t)E_DIM * E_DIM * sizeof(bf16);   // 8 MiB (weights)
  bf16* xb   = (bf16*)(ws + 0 * BUF);          // [B,S,E] bf16 x
  bf16* qb   = (bf16*)(ws + 1 * BUF);          // [B,H,S,D]
  bf16* kb   = (bf16*)(ws + 2 * BUF);          // [B,H,S,D]
  bf16* vtb  = (bf16*)(ws + 3 * BUF);          // [B,H,D,S]
  bf16* tqb  = (bf16*)(ws + 4 * BUF);          // [B,H,S,D]
  bf16* attb = (bf16*)(ws + 5 * BUF);          // [B,S,E] combined
  bf16* nrmb = qb;                             // alias: qb dead after attention
  uint8_t* wp = ws + 6 * BUF;
  bf16* Wqb  = (bf16*)(wp + 0 * WBUF);
  bf16* Wkb  = (bf16*)(wp + 1 * WBUF);
  bf16* Wvb  = (bf16*)(wp + 2 * WBUF);
  bf16* Wtqb = (bf16*)(wp + 3 * WBUF);
  bf16* Wob  = (bf16*)(wp + 4 * WBUF);
  float* tkb = (float*)(wp + 5 * WBUF);               // [8][E] f32
  float* tvb = (float*)(wp + 5 * WBUF + 128 * 1024);  // [8][E] f32

  // --- convert f32 -> bf16 for MFMA consumers ---
  const int WN8 = E_DIM * E_DIM / 8;   // 524288
  const int XN8 = NTOK * E_DIM / 8;    // 1048576
  cvt_f32_bf16_kernel<<<dim3(2048), 256, 0, stream>>>(x, xb, XN8);
  cvt_f32_bf16_kernel<<<dim3(1024), 256, 0, stream>>>(Wq, Wqb, WN8);
  cvt_f32_bf16_kernel<<<dim3(1024), 256, 0, stream>>>(Wk, Wkb, WN8);
  cvt_f32_bf16_kernel<<<dim3(1024), 256, 0, stream>>>(Wv, Wvb, WN8);
  cvt_f32_bf16_kernel<<<dim3(1024), 256, 0, stream>>>(Wtq, Wtqb, WN8);
  cvt_f32_bf16_kernel<<<dim3(1024), 256, 0, stream>>>(Wo, Wob, WN8);

  // --- projections ---
  ProjArgs pa;
  pa.W[0] = Wqb;  pa.bias[0] = bq;  pa.out[0] = qb;  pa.mode[0] = 1;
  pa.W[1] = Wkb;  pa.bias[1] = bk;  pa.out[1] = kb;  pa.mode[1] = 1;
  pa.W[2] = Wvb;  pa.bias[2] = bv;  pa.out[2] = vtb; pa.mode[2] = 2;
  pa.W[3] = Wtqb; pa.bias[3] = btq; pa.out[3] = tqb; pa.mode[3] = 1;
  gemm_nt_kernel<<<dim3(NTOK / 128, E_DIM / 128, 4), 256, 0, stream>>>(
      xb, pa, NTOK, E_DIM, E_DIM);

  slots_proj_kernel<<<dim3(E_DIM / 256, NSLOT, 2), 256, 0, stream>>>(
      slots, Wtk, btk, Wtv, btv, tkb, tvb);

  // --- attention streams ---
  flash_attn_kernel<<<dim3(SEQ / 128, BATCH * HEADS), 256, 0, stream>>>(
      qb, kb, vtb, attb);
  thought_attn_kernel<<<dim3(BATCH * HEADS * SEQ / 4), 256, 0, stream>>>(
      tqb, tkb, tvb, attb);

  // --- layernorm + output projection ---
  layernorm_kernel<<<dim3(NTOK), 256, 0, stream>>>(attb, gamma, beta, nrmb);

  ProjArgs po;
  po.W[0] = Wob; po.bias[0] = bo; po.out[0] = d_out; po.mode[0] = 0;
  po.W[1] = po.W[2] = po.W[3] = Wob;
  po.bias[1] = po.bias[2] = po.bias[3] = bo;
  po.out[1] = po.out[2] = po.out[3] = d_out;
  po.mode[1] = po.mode[2] = po.mode[3] = 0;
  gemm_nt_kernel<<<dim3(NTOK / 128, E_DIM / 128, 1), 256, 0, stream>>>(
      nrmb, po, NTOK, E_DIM, E_DIM);
}

// Round 3
// 528.717 us; speedup vs baseline: 1.0825x; 1.0825x over previous
//
#include <hip/hip_runtime.h>
#include <hip/hip_bf16.h>
#include <stdint.h>

typedef __bf16 bf16;
typedef __bf16 bf16x8 __attribute__((ext_vector_type(8)));
typedef __bf16 bf16x4 __attribute__((ext_vector_type(4)));
typedef float f32x4 __attribute__((ext_vector_type(4)));

#define E_DIM 2048
#define HEADS 16
#define HD 128
#define SEQ 2048
#define BATCH 2
#define NTOK 4096
#define NSLOT 8

// 1/sqrt(128) * log2(e): folded into Q / TQ at projection time
#define QSCALE (0.08838834764831845f * 1.4426950408889634f)

__device__ __forceinline__ void gload_lds16(const void* g, void* lds) {
  __builtin_amdgcn_global_load_lds(
      (const __attribute__((address_space(1))) uint32_t*)g,
      (__attribute__((address_space(3))) uint32_t*)lds, 16, 0, 0);
}

// ---------------- f32 -> bf16 convert, 8 elems/thread, grid-stride ----------------
__global__ __launch_bounds__(256) void cvt_f32_bf16_kernel(
    const float* __restrict__ src, bf16* __restrict__ dst, int n8)
{
  for (int i = blockIdx.x * 256 + threadIdx.x; i < n8; i += gridDim.x * 256) {
    const f32x4 a = *(const f32x4*)(src + i * 8);
    const f32x4 b = *(const f32x4*)(src + i * 8 + 4);
    bf16x8 o;
#pragma unroll
    for (int j = 0; j < 4; j++) { o[j] = (bf16)a[j]; o[4 + j] = (bf16)b[j]; }
    *(bf16x8*)(dst + i * 8) = o;
  }
}

struct ProjArgs {
  const bf16* W[4];
  const float* bias[4];
  void* out[4];
  int mode[4];     // 0: f32 row-major [M][N]; 1: bf16 [B,H,S,D]; 2: bf16 [B,H,D,S]
  float scale[4];  // applied AFTER bias: out = (acc+bias)*scale
};

// ---------------- NT GEMM: C = (A @ W^T + bias)*scale, bf16 in, fp32 acc ----------------
// A [M][K] row-major bf16, W [N][K] row-major bf16. 128x128 tile, BK=32, 4 waves.
// Double-buffered LDS, stage-early / single barrier per K-tile (T3-minimum).
__global__ __launch_bounds__(256) void gemm_nt_kernel(
    const bf16* __restrict__ A, ProjArgs pa, int M, int N, int K)
{
  __shared__ bf16 As[2][128 * 32];
  __shared__ bf16 Bs[2][128 * 32];

  const int z = blockIdx.z;
  const bf16* __restrict__ W = pa.W[z];
  const float* __restrict__ bias = pa.bias[z];
  void* __restrict__ out = pa.out[z];
  const int mode = pa.mode[z];
  const float scale = pa.scale[z];

  const int tid = threadIdx.x;
  const int lane = tid & 63;
  const int w = tid >> 6;
  const int wr = w >> 1, wc = w & 1;
  const int g = lane >> 4, c = lane & 15;
  const int bm = blockIdx.x, bn = blockIdx.y;

  f32x4 acc[4][4] = {};

  const int srow = lane >> 2;          // 0..15
  const int scol = (lane & 3) * 8;     // 0,8,16,24
  const bf16* Ab = A + (size_t)(bm * 128 + srow) * K + scol;
  const bf16* Wb = W + (size_t)(bn * 128 + srow) * K + scol;

  auto stage = [&](int k0, int buf) {
#pragma unroll
    for (int i = 0; i < 2; ++i) {
      const int chunk = w * 2 + i;     // 0..7, each 1024B = 16 rows x 32 cols
      gload_lds16(Ab + (size_t)(chunk * 16) * K + k0, (char*)(&As[buf][0]) + chunk * 1024);
      gload_lds16(Wb + (size_t)(chunk * 16) * K + k0, (char*)(&Bs[buf][0]) + chunk * 1024);
    }
  };

  stage(0, 0);
  __syncthreads();
  int cur = 0;

  for (int k0 = 0; k0 < K; k0 += 32) {
    if (k0 + 32 < K) stage(k0 + 32, cur ^ 1);   // issue next tile BEFORE compute
    bf16x8 af[4], bfr[4];
#pragma unroll
    for (int m = 0; m < 4; m++)
      af[m] = *(const bf16x8*)(&As[cur][0] + (wr * 64 + m * 16 + c) * 32 + g * 8);
#pragma unroll
    for (int n = 0; n < 4; n++)
      bfr[n] = *(const bf16x8*)(&Bs[cur][0] + (wc * 64 + n * 16 + c) * 32 + g * 8);
#pragma unroll
    for (int m = 0; m < 4; m++)
#pragma unroll
      for (int n = 0; n < 4; n++)
        acc[m][n] = __builtin_amdgcn_mfma_f32_16x16x32_bf16(af[m], bfr[n], acc[m][n], 0, 0, 0);
    __syncthreads();                             // drains own vmcnt + lgkm, then barrier
    cur ^= 1;
  }

  // epilogue: D[r][c]: col = lane&15, row = (lane>>4)*4 + j
#pragma unroll
  for (int m = 0; m < 4; m++) {
#pragma unroll
    for (int n = 0; n < 4; n++) {
      const int col = bn * 128 + wc * 64 + n * 16 + c;
      const float bv = bias[col];
#pragma unroll
      for (int j = 0; j < 4; j++) {
        const int row = bm * 128 + wr * 64 + m * 16 + g * 4 + j;
        const float v = (acc[m][n][j] + bv) * scale;
        if (mode == 0) {
          ((float*)out)[(size_t)row * N + col] = v;
        } else {
          const int b = row >> 11, s = row & 2047;
          const int h = col >> 7, d = col & 127;
          size_t idx;
          if (mode == 1) idx = (((size_t)(b * HEADS + h)) * SEQ + s) * HD + d;
          else           idx = (((size_t)(b * HEADS + h)) * HD + d) * SEQ + s;
          ((bf16*)out)[idx] = (bf16)v;
        }
      }
    }
  }
}

// ---------------- slots projections: tk/tv = slots @ W^T + b, f32 [8][2048] ----------------
__global__ __launch_bounds__(256) void slots_proj_kernel(
    const float* __restrict__ slots,
    const float* __restrict__ Wk, const float* __restrict__ bk,
    const float* __restrict__ Wv, const float* __restrict__ bv,
    float* __restrict__ tk, float* __restrict__ tv)
{
  const int col = blockIdx.x * 256 + threadIdx.x;
  const int slot = blockIdx.y;
  const int mat = blockIdx.z;
  const float* W = mat ? Wv : Wk;
  const float* bias = mat ? bv : bk;
  float* out = mat ? tv : tk;
  const float* xr = slots + (size_t)slot * E_DIM;
  const float* wr = W + (size_t)col * E_DIM;
  float acc = 0.f;
  for (int k = 0; k < E_DIM; k += 4) {
    const f32x4 a = *(const f32x4*)(xr + k);
    const f32x4 b4 = *(const f32x4*)(wr + k);
#pragma unroll
    for (int i = 0; i < 4; i++) acc += a[i] * b4[i];
  }
  out[(size_t)slot * E_DIM + col] = acc + bias[col];
}

// ---------------- flash attention (full, no mask) ----------------
// Q pre-scaled by QSCALE. Q,K: bf16 [B,H,S,D]; Vt: bf16 [B,H,D,S]; out: bf16 [B,S,E].
// 4 waves, 128 q rows (32/wave). KV tile 64, double-buffered, stage-early.
// 1D grid (512 blocks), XCD-chunked swizzle so each XCD owns 4 bh's K/V.
__global__ __launch_bounds__(256) void flash_attn_kernel(
    const bf16* __restrict__ Qg, const bf16* __restrict__ Kg,
    const bf16* __restrict__ Vtg, bf16* __restrict__ Og)
{
  __shared__ char Ks[2][64 * 256];    // [kv][d] bf16, 256B rows, XOR-swizzled
  __shared__ char Vs[2][128 * 128];   // [d][kv] bf16, 128B rows, XOR-swizzled
  __shared__ char Ps[4][4096];        // per-wave [q32][kv64] bf16, swizzled

  const int orig = blockIdx.x;                 // 512 blocks
  const int logical = (orig & 7) * 64 + (orig >> 3);   // XCD k -> bh in [4k,4k+4)
  const int qt = logical & 15;
  const int bh = logical >> 4;

  const int tid = threadIdx.x;
  const int lane = tid & 63;
  const int w = tid >> 6;
  const int g = lane >> 4, c = lane & 15;
  const int b = bh >> 4, h = bh & 15;
  const int q0 = qt * 128 + w * 32;

  const bf16* Qb = Qg + ((size_t)bh * SEQ + q0) * HD;
  const bf16* Kb = Kg + (size_t)bh * SEQ * HD;
  const bf16* Vb = Vtg + (size_t)bh * HD * SEQ;
  char* Pw = Ps[w];

  auto stage = [&](int kv0, int buf) {
#pragma unroll
    for (int i = 0; i < 4; i++) {
      const int chunk = w * 4 + i;
      const int p = chunk * 1024 + lane * 16;
      {
        const int r = p >> 8;                       // kv row
        const int sl = ((p >> 4) & 15) ^ (r & 7);   // 16B slot within row
        gload_lds16(Kb + (size_t)(kv0 + r) * HD + sl * 8, &Ks[buf][0] + chunk * 1024);
      }
      {
        const int r = p >> 7;                       // d row
        const int sl = ((p >> 4) & 7) ^ (r & 7);
        gload_lds16(Vb + (size_t)r * SEQ + kv0 + sl * 8, &Vs[buf][0] + chunk * 1024);
      }
    }
  };

  // Q fragments (B operand), pre-scaled: qf[kk][n][j] = Q[n*16+c][kk*32+g*8+j]
  bf16x8 qf[4][2];
#pragma unroll
  for (int kk = 0; kk < 4; kk++)
#pragma unroll
    for (int n = 0; n < 2; n++)
      qf[kk][n] = *(const bf16x8*)(Qb + (size_t)(n * 16 + c) * HD + kk * 32 + g * 8);

  stage(0, 0);
  __syncthreads();
  int cur = 0;

  f32x4 acc[2][8] = {};
  float mrun[2] = {-1e30f, -1e30f};
  float lrun[2] = {0.f, 0.f};

  for (int kv0 = 0; kv0 < SEQ; kv0 += 64) {
    if (kv0 + 64 < SEQ) stage(kv0 + 64, cur ^ 1);   // issue next K/V tile first

    // S^T[kv][q] = K · Q^T  (scores already in log2 domain via pre-scaled Q)
    f32x4 st[4][2] = {};
#pragma unroll
    for (int kk = 0; kk < 4; kk++) {
      bf16x8 kf[4];
#pragma unroll
      for (int kfr = 0; kfr < 4; kfr++) {
        const int r = kfr * 16 + c;
        const int sl = (kk * 4 + g) ^ (r & 7);
        kf[kfr] = *(const bf16x8*)(&Ks[cur][0] + r * 256 + sl * 16);
      }
      __builtin_amdgcn_s_setprio(1);
#pragma unroll
      for (int kfr = 0; kfr < 4; kfr++)
#pragma unroll
        for (int n = 0; n < 2; n++)
          st[kfr][n] = __builtin_amdgcn_mfma_f32_16x16x32_bf16(kf[kfr], qf[kk][n], st[kfr][n], 0, 0, 0);
      __builtin_amdgcn_s_setprio(0);
    }

    // online softmax; lane holds kv = kfr*16 + g*4 + j for q = n*16 + c
    float fsc[2];
#pragma unroll
    for (int n = 0; n < 2; n++) {
      float lm = -1e30f;
#pragma unroll
      for (int kfr = 0; kfr < 4; kfr++)
#pragma unroll
        for (int j = 0; j < 4; j++) lm = fmaxf(lm, st[kfr][n][j]);
      lm = fmaxf(lm, __shfl_xor(lm, 16));
      lm = fmaxf(lm, __shfl_xor(lm, 32));
      const float mn = fmaxf(mrun[n], lm);
      fsc[n] = exp2f(mrun[n] - mn);
      mrun[n] = mn;
      float ps = 0.f;
#pragma unroll
      for (int kfr = 0; kfr < 4; kfr++)
#pragma unroll
        for (int j = 0; j < 4; j++) {
          const float pp = exp2f(st[kfr][n][j] - mn);
          st[kfr][n][j] = pp;
          ps += pp;
        }
      ps += __shfl_xor(ps, 16);
      ps += __shfl_xor(ps, 32);
      lrun[n] = lrun[n] * fsc[n] + ps;
    }

    // rescale O accumulator: acc[m][*] row q = m*16 + g*4 + j
#pragma unroll
    for (int m = 0; m < 2; m++)
#pragma unroll
      for (int j = 0; j < 4; j++) {
        const float fj = __shfl(fsc[m], (lane & 48) | (g * 4 + j));
#pragma unroll
        for (int n = 0; n < 8; n++) acc[m][n][j] *= fj;
      }

    // write P (bf16) to per-wave LDS [q][kv], swizzled
#pragma unroll
    for (int n = 0; n < 2; n++)
#pragma unroll
      for (int kfr = 0; kfr < 4; kfr++) {
        bf16x4 pk;
#pragma unroll
        for (int j = 0; j < 4; j++) pk[j] = (bf16)st[kfr][n][j];
        const int q = n * 16 + c;
        const int L = q * 128 + kfr * 32 + g * 8;
        *(bf16x4*)(Pw + (L ^ ((q & 7) << 4))) = pk;
      }

    // O += P · V : A = P[q][kv], B = Vt[d][kv]
#pragma unroll
    for (int kk = 0; kk < 2; kk++) {
      bf16x8 pf[2];
#pragma unroll
      for (int m = 0; m < 2; m++) {
        const int q = m * 16 + c;
        const int L = q * 128 + kk * 64 + g * 16;
        pf[m] = *(const bf16x8*)(Pw + (L ^ ((q & 7) << 4)));
      }
      __builtin_amdgcn_s_setprio(1);
#pragma unroll
      for (int n = 0; n < 8; n++) {
        const int d = n * 16 + c;
        const int Lv = d * 128 + kk * 64 + g * 16;
        const bf16x8 vf = *(const bf16x8*)(&Vs[cur][0] + (Lv ^ ((d & 7) << 4)));
#pragma unroll
        for (int m = 0; m < 2; m++)
          acc[m][n] = __builtin_amdgcn_mfma_f32_16x16x32_bf16(pf[m], vf, acc[m][n], 0, 0, 0);
      }
      __builtin_amdgcn_s_setprio(0);
    }

    __syncthreads();   // single barrier per tile: drains own staging vmcnt, guards dbuf reuse
    cur ^= 1;
  }

  // epilogue: normalize and write [B,S,E]
#pragma unroll
  for (int m = 0; m < 2; m++) {
#pragma unroll
    for (int j = 0; j < 4; j++) {
      const float lb = __shfl(lrun[m], (lane & 48) | (g * 4 + j));
      const float linv = 1.0f / lb;
      const int s = q0 + m * 16 + g * 4 + j;
#pragma unroll
      for (int n = 0; n < 8; n++) {
        const int e = h * HD + n * 16 + c;
        Og[((size_t)b * SEQ + s) * E_DIM + e] = (bf16)(acc[m][n][j] * linv);
      }
    }
  }
}

// ---------------- fused thought cross-attn + LayerNorm ----------------
// One block per token. TQ bf16 [B,H,S,D] pre-scaled by QSCALE; TK,TV f32 [8][E];
// ATT bf16 [B,S,E] (flash output); writes Y = LN(ATT + thought) bf16.
__global__ __launch_bounds__(256) void thought_ln_kernel(
    const bf16* __restrict__ TQ, const float* __restrict__ TK,
    const float* __restrict__ TV, const bf16* __restrict__ ATT,
    const float* __restrict__ gamma, const float* __restrict__ beta,
    bf16* __restrict__ Y)
{
  __shared__ float wsum[4], wsq[4];
  const int tid = threadIdx.x;
  const int lane = tid & 63;
  const int w = tid >> 6;
  const int tok = blockIdx.x;            // b*SEQ + s
  const int b = tok >> 11, s = tok & 2047;
  const int e0 = tid * 8;
  const int h = e0 >> 7;
  const int d0 = e0 & 127;

  // attention row
  const bf16x8 av = *(const bf16x8*)(ATT + (size_t)tok * E_DIM + e0);
  float v[8];
#pragma unroll
  for (int i = 0; i < 8; i++) v[i] = (float)av[i];

  // thought-query fragment for this head (pre-scaled -> dots in log2 domain)
  const bf16x8 qv8 = *(const bf16x8*)(TQ + (((size_t)(b * HEADS + h)) * SEQ + s) * HD + d0);
  float qv[8];
#pragma unroll
  for (int i = 0; i < 8; i++) qv[i] = (float)qv8[i];

  // dots with each slot's key (head h chunk), reduced over the 16-lane head group
  float dts[NSLOT];
#pragma unroll
  for (int sl = 0; sl < NSLOT; sl++) {
    const float* tkr = TK + (size_t)sl * E_DIM + e0;
    const f32x4 k0 = *(const f32x4*)(tkr);
    const f32x4 k1 = *(const f32x4*)(tkr + 4);
    float dp = 0.f;
#pragma unroll
    for (int i = 0; i < 4; i++) dp += qv[i] * k0[i] + qv[4 + i] * k1[i];
    dp += __shfl_xor(dp, 1);
    dp += __shfl_xor(dp, 2);
    dp += __shfl_xor(dp, 4);
    dp += __shfl_xor(dp, 8);
    dts[sl] = dp;
  }
  float mx = dts[0];
#pragma unroll
  for (int sl = 1; sl < NSLOT; sl++) mx = fmaxf(mx, dts[sl]);
  float p[NSLOT], den = 0.f;
#pragma unroll
  for (int sl = 0; sl < NSLOT; sl++) { p[sl] = exp2f(dts[sl] - mx); den += p[sl]; }
  const float dinv = 1.0f / den;
#pragma unroll
  for (int sl = 0; sl < NSLOT; sl++) {
    const float pn = p[sl] * dinv;
    const float* tvr = TV + (size_t)sl * E_DIM + e0;
    const f32x4 v0 = *(const f32x4*)(tvr);
    const f32x4 v1 = *(const f32x4*)(tvr + 4);
#pragma unroll
    for (int i = 0; i < 4; i++) { v[i] += pn * v0[i]; v[4 + i] += pn * v1[i]; }
  }

  // layernorm over E
  float sm = 0.f, sq = 0.f;
#pragma unroll
  for (int i = 0; i < 8; i++) { sm += v[i]; sq += v[i] * v[i]; }
#pragma unroll
  for (int d = 1; d < 64; d <<= 1) { sm += __shfl_xor(sm, d); sq += __shfl_xor(sq, d); }
  if (lane == 0) { wsum[w] = sm; wsq[w] = sq; }
  __syncthreads();
  const float ts = wsum[0] + wsum[1] + wsum[2] + wsum[3];
  const float tq2 = wsq[0] + wsq[1] + wsq[2] + wsq[3];
  const float mean = ts * (1.f / E_DIM);
  const float var = tq2 * (1.f / E_DIM) - mean * mean;
  const float rstd = rsqrtf(var + 1e-5f);
  const f32x4 g0 = *(const f32x4*)(gamma + e0);
  const f32x4 g1 = *(const f32x4*)(gamma + e0 + 4);
  const f32x4 b0 = *(const f32x4*)(beta + e0);
  const f32x4 b1 = *(const f32x4*)(beta + e0 + 4);
  bf16x8 outv;
#pragma unroll
  for (int i = 0; i < 4; i++) {
    outv[i]     = (bf16)((v[i]     - mean) * rstd * g0[i] + b0[i]);
    outv[4 + i] = (bf16)((v[4 + i] - mean) * rstd * g1[i] + b1[i]);
  }
  *(bf16x8*)(Y + (size_t)tok * E_DIM + e0) = outv;
}

extern "C" void kernel_launch(void* const* d_in, const int* in_sizes, int n_in,
                              void* d_out, int out_size, void* d_ws, size_t ws_size,
                              hipStream_t stream) {
  (void)in_sizes; (void)n_in; (void)out_size; (void)ws_size;
  const float* x     = (const float*)d_in[0];
  const float* slots = (const float*)d_in[1];
  const float* Wq  = (const float*)d_in[2];   const float* bq  = (const float*)d_in[3];
  const float* Wk  = (const float*)d_in[4];   const float* bk  = (const float*)d_in[5];
  const float* Wv  = (const float*)d_in[6];   const float* bv  = (const float*)d_in[7];
  const float* Wtq = (const float*)d_in[8];   const float* btq = (const float*)d_in[9];
  const float* Wtk = (const float*)d_in[10];  const float* btk = (const float*)d_in[11];
  const float* Wtv = (const float*)d_in[12];  const float* btv = (const float*)d_in[13];
  const float* Wo  = (const float*)d_in[14];  const float* bo  = (const float*)d_in[15];
  const float* gamma = (const float*)d_in[16];
  const float* beta  = (const float*)d_in[17];

  uint8_t* ws = (uint8_t*)d_ws;
  const size_t BUF  = (size_t)NTOK * E_DIM * sizeof(bf16);    // 16 MiB (activations)
  const size_t WBUF = (size_t)E_DIM * E_DIM * sizeof(bf16);   // 8 MiB (weights)
  bf16* xb   = (bf16*)(ws + 0 * BUF);          // [B,S,E] bf16 x
  bf16* qb   = (bf16*)(ws + 1 * BUF);          // [B,H,S,D] (pre-scaled)
  bf16* kb   = (bf16*)(ws + 2 * BUF);          // [B,H,S,D]
  bf16* vtb  = (bf16*)(ws + 3 * BUF);          // [B,H,D,S]
  bf16* tqb  = (bf16*)(ws + 4 * BUF);          // [B,H,S,D] (pre-scaled)
  bf16* attb = (bf16*)(ws + 5 * BUF);          // [B,S,E] flash output
  bf16* nrmb = qb;                             // alias: qb dead after flash
  uint8_t* wp = ws + 6 * BUF;
  bf16* Wqb  = (bf16*)(wp + 0 * WBUF);
  bf16* Wkb  = (bf16*)(wp + 1 * WBUF);
  bf16* Wvb  = (bf16*)(wp + 2 * WBUF);
  bf16* Wtqb = (bf16*)(wp + 3 * WBUF);
  bf16* Wob  = (bf16*)(wp + 4 * WBUF);
  float* tkb = (float*)(wp + 5 * WBUF);               // [8][E] f32
  float* tvb = (float*)(wp + 5 * WBUF + 128 * 1024);  // [8][E] f32

  // --- convert f32 -> bf16 for MFMA consumers ---
  const int WN8 = E_DIM * E_DIM / 8;   // 524288
  const int XN8 = NTOK * E_DIM / 8;    // 1048576
  cvt_f32_bf16_kernel<<<dim3(2048), 256, 0, stream>>>(x, xb, XN8);
  cvt_f32_bf16_kernel<<<dim3(1024), 256, 0, stream>>>(Wq, Wqb, WN8);
  cvt_f32_bf16_kernel<<<dim3(1024), 256, 0, stream>>>(Wk, Wkb, WN8);
  cvt_f32_bf16_kernel<<<dim3(1024), 256, 0, stream>>>(Wv, Wvb, WN8);
  cvt_f32_bf16_kernel<<<dim3(1024), 256, 0, stream>>>(Wtq, Wtqb, WN8);
  cvt_f32_bf16_kernel<<<dim3(1024), 256, 0, stream>>>(Wo, Wob, WN8);

  // --- projections (Q and TQ pre-scaled by 1/sqrt(D)*log2e) ---
  ProjArgs pa;
  pa.W[0] = Wqb;  pa.bias[0] = bq;  pa.out[0] = qb;  pa.mode[0] = 1; pa.scale[0] = QSCALE;
  pa.W[1] = Wkb;  pa.bias[1] = bk;  pa.out[1] = kb;  pa.mode[1] = 1; pa.scale[1] = 1.0f;
  pa.W[2] = Wvb;  pa.bias[2] = bv;  pa.out[2] = vtb; pa.mode[2] = 2; pa.scale[2] = 1.0f;
  pa.W[3] = Wtqb; pa.bias[3] = btq; pa.out[3] = tqb; pa.mode[3] = 1; pa.scale[3] = QSCALE;
  gemm_nt_kernel<<<dim3(NTOK / 128, E_DIM / 128, 4), 256, 0, stream>>>(
      xb, pa, NTOK, E_DIM, E_DIM);

  slots_proj_kernel<<<dim3(E_DIM / 256, NSLOT, 2), 256, 0, stream>>>(
      slots, Wtk, btk, Wtv, btv, tkb, tvb);

  // --- attention streams ---
  flash_attn_kernel<<<dim3((SEQ / 128) * BATCH * HEADS), 256, 0, stream>>>(
      qb, kb, vtb, attb);
  thought_ln_kernel<<<dim3(NTOK), 256, 0, stream>>>(
      tqb, tkb, tvb, attb, gamma, beta, nrmb);

  // --- output projection (f32 out) ---
  ProjArgs po;
  po.W[0] = Wob; po.bias[0] = bo; po.out[0] = d_out; po.mode[0] = 0; po.scale[0] = 1.0f;
  po.W[1] = po.W[2] = po.W[3] = Wob;
  po.bias[1] = po.bias[2] = po.bias[3] = bo;
  po.out[1] = po.out[2] = po.out[3] = d_out;
  po.mode[1] = po.mode[2] = po.mode[3] = 0;
  po.scale[1] = po.scale[2] = po.scale[3] = 1.0f;
  gemm_nt_kernel<<<dim3(NTOK / 128, E_DIM / 128, 1), 256, 0, stream>>>(
      nrmb, po, NTOK, E_DIM, E_DIM);
}